// Round 6
// baseline (974.305 us; speedup 1.0000x reference)
//
#include <hip/hip_runtime.h>
#include <hip/hip_bf16.h>
#include <stdint.h>

#define MM 4096
#define KK 4096
#define NN 11008
#define NP8 1376      // NN/8
#define GRP 128

typedef short v8s __attribute__((ext_vector_type(8)));
typedef float v4f __attribute__((ext_vector_type(4)));

__device__ __forceinline__ void async_cp16(const void* g, void* l) {
  __builtin_amdgcn_global_load_lds(
      (const __attribute__((address_space(1))) unsigned int*)g,
      (__attribute__((address_space(3))) unsigned int*)l, 16, 0, 0);
}

// ---------- x fp32 -> bf16 (one-time) ----------
__global__ void cvt_x_kernel(const float* __restrict__ x,
                             __hip_bfloat16* __restrict__ x16) {
  size_t i = ((size_t)blockIdx.x * 256 + threadIdx.x) * 8;
  const float4* p = (const float4*)(x + i);
  float4 a = p[0], b = p[1];
  union { __hip_bfloat16 h[8]; v8s v; } u;
  u.h[0] = __float2bfloat16(a.x); u.h[1] = __float2bfloat16(a.y);
  u.h[2] = __float2bfloat16(a.z); u.h[3] = __float2bfloat16(a.w);
  u.h[4] = __float2bfloat16(b.x); u.h[5] = __float2bfloat16(b.y);
  u.h[6] = __float2bfloat16(b.z); u.h[7] = __float2bfloat16(b.w);
  *(v8s*)(x16 + i) = u.v;
}

// ---------- R6: fused dequant-in-GEMM, 256x256, quadrant walk ----------
// R1-R5 schedule family closed at 43-47% MfmaUtil. This round removes the
// Wt round-trip entirely: B is staged as RAW int4 words (qs: 8KB/K-tile via
// global_load_lds, 4x less fetch) and dequantized in-kernel at p3 (the
// quadrant walk's read-free phase) into the swizzled Bs buffer for tile t+1.
// LDS 144K: As 2x32K | Bs 2x32K | qs 2x8K. Deletes dequant kernel + 90MB
// Wt write + ~300MB HBM re-fetch.
// Pipeline (per tile t, buf=t&1):
//   p0: frag A-mh0(8)+B-nh0(4); lgkm(8); bar; lgkm0; MFMA Q0; bar
//   p1: frag B-nh1(4); stA(h0,t+1); [even t: prefetch s/z group t/2+1]; ...Q1
//   p2: frag A-mh1(8); stA(h1,t+1); MFMA Q2; vmcnt(6|4) gate BEFORE bar
//       (retires qw[t+1] in EVERY wave before the shared barrier -> qs reads
//        at p3 are cross-wave safe)
//   p3: dequant qs[(t+1)&1] -> Bs[(t+1)&1] (32 ds_read_b32 broadcast-clean +
//       ~170 VALU + 4 swizzled ds_write_b128); issue qw[t+2] (NEWEST in FIFO
//       so end vmcnt(1) keeps it while draining A); bar; MFMA Q3;
//       vmcnt(1|0); lgkm(0); end-bar
// s/z: one (scale, 128+zero) pair per thread (its fixed column n0+dn),
// double-buffered in regs, rotated at odd tiles.
__global__ __launch_bounds__(512, 2)
void gemm_fused(const __hip_bfloat16* __restrict__ x16,
                const int* __restrict__ qw,
                const int* __restrict__ zeros,
                const float* __restrict__ scales,
                const float* __restrict__ bias,
                float* __restrict__ out) {
  __shared__ __align__(16) char lds[147456];  // As 0..64K, Bs 64K..128K, qs 128K..144K
  const int tid = threadIdx.x;
  const int wave = tid >> 6;
  const int lane = tid & 63;
  const int quad = lane >> 4;
  const int l16 = lane & 15;
  const int wm = (wave >> 2) * 128;     // 2 M-waves
  const int wn = (wave & 3) * 64;       // 4 N-waves
  const int m0 = blockIdx.x * 256;      // m-fast grid
  const int n0 = blockIdx.y * 256;
  const int swz = (l16 & 7) << 4;
  const int NT = KK / 64;
  const int BS_OFF = 65536, QS_OFF = 131072;

  // fragment read bases (chunk XOR folded once; in-loop reads base+imm)
  const int xof0 = (quad * 16) ^ swz;
  const int xof1 = (64 + quad * 16) ^ swz;
  const int aRow0 = (wm + l16) * 128 + xof0;
  const int aRow1 = (wm + l16) * 128 + xof1;
  const int bRow0 = BS_OFF + (wn + l16) * 128 + xof0;
  const int bRow1 = BS_OFF + (wn + l16) * 128 + xof1;

  // A staging: uniform base + one 32-bit per-thread offset (R3-verified)
  const char* aBase = (const char*)x16 + (size_t)m0 * (KK * 2);
  const int vrow = tid >> 3;
  const int jl = (tid & 7) ^ (vrow & 7);       // inverse swizzle on source
  const int voff = vrow * (KK * 2) + jl * 16;
  auto stA = [&](int bf_, int h, int ko) {
#pragma unroll
    for (int pp = 0; pp < 2; ++pp)
      async_cp16(aBase + ko + (h * 128 + pp * 64) * (KK * 2) + voff,
                 lds + bf_ * 32768 + h * 16384 + pp * 8192 + tid * 16);
  };

  // qw staging: linear (no swizzle needed: dequant reads are 8-word
  // broadcast across the wave -> 8 distinct banks, conflict-free)
  const char* qSrc = (const char*)qw + (size_t)(tid >> 3) * (NP8 * 4) +
                     (n0 >> 3) * 4 + (tid & 7) * 16;
  auto stQ = [&](int X) {
    async_cp16(qSrc + (size_t)X * (64 * NP8 * 4),
               lds + QS_OFF + (X & 1) * 8192 + tid * 16);
  };

  // dequant thread mapping: one column n = n0+dn, k-half dkh (32 k each)
  const int dn = tid & 255;
  const int dkh = tid >> 8;
  const int dn8 = dn >> 3;
  const int dj4 = (dn & 7) << 2;
  const int dqBase = QS_OFF + dkh * 4096 + dn8 * 4;   // + qpar*8192 + k*128
  const int dbBase = BS_OFF + dn * 128;               // + bpar*32768 + chunk
  float sC = scales[n0 + dn];
  float zC = 128.0f + (float)zeros[n0 + dn];
  float sN = 0.f, zN = 0.f;

#define DEQ(QPAR, SU, ZU)                                                   \
  do {                                                                      \
    const int qb = dqBase + (QPAR) * 8192;                                  \
    const int bb = dbBase + (QPAR) * 32768;                                 \
    _Pragma("unroll") for (int c8 = 0; c8 < 4; ++c8) {                      \
      union { __hip_bfloat16 h[8]; v8s v; } u;                              \
      _Pragma("unroll") for (int ii = 0; ii < 8; ++ii) {                    \
        int q = *(const int*)(lds + qb + (c8 * 8 + ii) * 128);              \
        unsigned nib = ((unsigned)q >> dj4) & 0xFu;                         \
        union { unsigned b; float f; } cc;                                  \
        cc.b = (0x4300u | nib) << 16;                                       \
        u.h[ii] = __float2bfloat16((cc.f - (ZU)) * (SU));                   \
      }                                                                     \
      *(v8s*)(lds + bb + (((dkh * 4 + c8) ^ (dn & 7)) << 4)) = u.v;         \
    }                                                                       \
  } while (0)

  v4f acc[8][4];
#pragma unroll
  for (int a = 0; a < 8; ++a)
#pragma unroll
    for (int b = 0; b < 4; ++b)
#pragma unroll
      for (int r = 0; r < 4; ++r) acc[a][b][r] = 0.f;

  // ---- prologue: qw[0],qw[1], A[0]; drain all; dequant B[0]; publish ----
  stQ(0); stQ(1);
  stA(0, 0, 0); stA(0, 1, 0);
  asm volatile("s_waitcnt vmcnt(0)" ::: "memory");
  __builtin_amdgcn_sched_barrier(0);
  __builtin_amdgcn_s_barrier();
  DEQ(0, sC, zC);
  asm volatile("s_waitcnt lgkmcnt(0)" ::: "memory");
  __builtin_amdgcn_sched_barrier(0);
  __builtin_amdgcn_s_barrier();

  for (int t = 0; t < NT; ++t) {
    const int buf = t & 1;
    const int ab = buf << 15;
    v8s aF[4][2], bF[4][2];

    // ---- p0: frag A-mh0(8) + B-nh0(4) ----
#pragma unroll
    for (int mi = 0; mi < 4; ++mi) {
      aF[mi][0] = *(const v8s*)(lds + ab + aRow0 + mi * 2048);
      aF[mi][1] = *(const v8s*)(lds + ab + aRow1 + mi * 2048);
    }
#pragma unroll
    for (int ni = 0; ni < 2; ++ni) {
      bF[ni][0] = *(const v8s*)(lds + ab + bRow0 + ni * 2048);
      bF[ni][1] = *(const v8s*)(lds + ab + bRow1 + ni * 2048);
    }
    asm volatile("s_waitcnt lgkmcnt(8)" ::: "memory");
    __builtin_amdgcn_sched_barrier(0);
    __builtin_amdgcn_s_barrier();
    asm volatile("s_waitcnt lgkmcnt(0)" ::: "memory");
    __builtin_amdgcn_sched_barrier(0);
    __builtin_amdgcn_s_setprio(1);
#pragma unroll
    for (int kk = 0; kk < 2; ++kk)
#pragma unroll
      for (int mi = 0; mi < 4; ++mi)
#pragma unroll
        for (int ni = 0; ni < 2; ++ni)
          acc[mi][ni] = __builtin_amdgcn_mfma_f32_16x16x32_bf16(
              aF[mi][kk], bF[ni][kk], acc[mi][ni], 0, 0, 0);
    __builtin_amdgcn_s_setprio(0);
    __builtin_amdgcn_sched_barrier(0);
    __builtin_amdgcn_s_barrier();

    // ---- p1: frag B-nh1(4); stA h0; s/z prefetch on even tiles ----
#pragma unroll
    for (int ni = 2; ni < 4; ++ni) {
      bF[ni][0] = *(const v8s*)(lds + ab + bRow0 + ni * 2048);
      bF[ni][1] = *(const v8s*)(lds + ab + bRow1 + ni * 2048);
    }
    if (t + 1 < NT) stA(buf ^ 1, 0, (t + 1) * 128);
    if (((t & 1) == 0) && t + 2 < NT) {
      int g = (t >> 1) + 1;
      sN = scales[(size_t)g * NN + n0 + dn];
      zN = 128.0f + (float)zeros[(size_t)g * NN + n0 + dn];
    }
    __builtin_amdgcn_sched_barrier(0);
    __builtin_amdgcn_s_barrier();
    asm volatile("s_waitcnt lgkmcnt(0)" ::: "memory");
    __builtin_amdgcn_sched_barrier(0);
    __builtin_amdgcn_s_setprio(1);
#pragma unroll
    for (int kk = 0; kk < 2; ++kk)
#pragma unroll
      for (int mi = 0; mi < 4; ++mi)
#pragma unroll
        for (int ni = 2; ni < 4; ++ni)
          acc[mi][ni] = __builtin_amdgcn_mfma_f32_16x16x32_bf16(
              aF[mi][kk], bF[ni][kk], acc[mi][ni], 0, 0, 0);
    __builtin_amdgcn_s_setprio(0);
    __builtin_amdgcn_sched_barrier(0);
    __builtin_amdgcn_s_barrier();

    // ---- p2: frag A-mh1(8); stA h1; Q2; dequant-gate vmcnt BEFORE bar ----
#pragma unroll
    for (int mi = 0; mi < 4; ++mi) {
      aF[mi][0] = *(const v8s*)(lds + ab + aRow0 + (mi + 4) * 2048);
      aF[mi][1] = *(const v8s*)(lds + ab + aRow1 + (mi + 4) * 2048);
    }
    if (t + 1 < NT) stA(buf ^ 1, 1, (t + 1) * 128);
    __builtin_amdgcn_sched_barrier(0);
    __builtin_amdgcn_s_barrier();
    asm volatile("s_waitcnt lgkmcnt(0)" ::: "memory");
    __builtin_amdgcn_sched_barrier(0);
    __builtin_amdgcn_s_setprio(1);
#pragma unroll
    for (int kk = 0; kk < 2; ++kk)
#pragma unroll
      for (int mi = 0; mi < 4; ++mi)
#pragma unroll
        for (int ni = 0; ni < 2; ++ni)
          acc[mi + 4][ni] = __builtin_amdgcn_mfma_f32_16x16x32_bf16(
              aF[mi][kk], bF[ni][kk], acc[mi + 4][ni], 0, 0, 0);
    __builtin_amdgcn_s_setprio(0);
    __builtin_amdgcn_sched_barrier(0);
    // gate: retire qw[t+1] in EVERY wave before the shared barrier.
    // FIFO after qw[t+1] (issued t-1 p3): Ah0(2,p1) + sz(2, even t) + Ah1(2,p2)
    if (t + 1 < NT) {
      if (((t & 1) == 0) && t + 2 < NT)
        asm volatile("s_waitcnt vmcnt(6)" ::: "memory");
      else
        asm volatile("s_waitcnt vmcnt(4)" ::: "memory");
    }
    __builtin_amdgcn_sched_barrier(0);
    __builtin_amdgcn_s_barrier();

    // ---- p3: dequant B[t+1]; issue qw[t+2] (newest); bar; Q3; drains ----
    if (t + 1 < NT) {
      if (t & 1) { DEQ((t + 1) & 1, sN, zN); }
      else       { DEQ((t + 1) & 1, sC, zC); }
      if (t & 1) { sC = sN; zC = zN; }
    }
    if (t + 2 < NT) stQ(t + 2);
    __builtin_amdgcn_sched_barrier(0);
    __builtin_amdgcn_s_barrier();
    __builtin_amdgcn_s_setprio(1);
#pragma unroll
    for (int kk = 0; kk < 2; ++kk)
#pragma unroll
      for (int mi = 0; mi < 4; ++mi)
#pragma unroll
        for (int ni = 2; ni < 4; ++ni)
          acc[mi + 4][ni] = __builtin_amdgcn_mfma_f32_16x16x32_bf16(
              aF[mi][kk], bF[ni][kk], acc[mi + 4][ni], 0, 0, 0);
    __builtin_amdgcn_s_setprio(0);
    __builtin_amdgcn_sched_barrier(0);
    // end drain: A[t+1] fully landed (qw[t+2] is newest -> kept in flight)
    if (t + 2 < NT) asm volatile("s_waitcnt vmcnt(1)" ::: "memory");
    else            asm volatile("s_waitcnt vmcnt(0)" ::: "memory");
    asm volatile("s_waitcnt lgkmcnt(0)" ::: "memory");
    __builtin_amdgcn_sched_barrier(0);
    __builtin_amdgcn_s_barrier();
  }

  // epilogue: C/D layout col=lane&15, row=quad*4+reg (m91-verified)
#pragma unroll
  for (int ni = 0; ni < 4; ++ni) {
    int col = n0 + wn + ni * 16 + l16;
    float bv = bias[col];
#pragma unroll
    for (int mi = 0; mi < 8; ++mi) {
      int rowb = m0 + wm + mi * 16 + quad * 4;
#pragma unroll
      for (int r = 0; r < 4; ++r)
        out[(size_t)(rowb + r) * NN + col] = acc[mi][ni][r] + bv;
    }
  }
#undef DEQ
}

// ---------- correct-but-slow fallback (only if ws is tiny) ----------
__global__ void fallback_kernel(const float* __restrict__ x,
                                const int* __restrict__ qw,
                                const int* __restrict__ zeros,
                                const float* __restrict__ scales,
                                const float* __restrict__ bias,
                                float* __restrict__ out) {
  __shared__ float xs[32][33];
  __shared__ int qs[32][4];
  __shared__ float ss[32];
  __shared__ float zz[32];
  int m0 = blockIdx.y * 32, n0 = blockIdx.x * 32;
  int t = threadIdx.x;
  int m_l = t >> 3, n_j = (t & 7) * 4;
  float acc[4] = {0.f, 0.f, 0.f, 0.f};
  for (int k0 = 0; k0 < KK; k0 += 32) {
    __syncthreads();
    for (int i = t; i < 1024; i += 256)
      xs[i >> 5][i & 31] = x[(size_t)(m0 + (i >> 5)) * KK + k0 + (i & 31)];
    if (t < 128) qs[t >> 2][t & 3] = qw[(size_t)(k0 + (t >> 2)) * NP8 + (n0 >> 3) + (t & 3)];
    int g = k0 / GRP;
    if (t < 32) {
      ss[t] = scales[(size_t)g * NN + n0 + t];
      zz[t] = (float)zeros[(size_t)g * NN + n0 + t];
    }
    __syncthreads();
    for (int kk = 0; kk < 32; ++kk) {
      float xv = xs[m_l][kk];
#pragma unroll
      for (int j = 0; j < 4; ++j) {
        int n_l = n_j + j;
        int q = qs[kk][n_l >> 3];
        float nib = (float)((q >> ((n_l & 7) * 4)) & 0xF);
        acc[j] += xv * (nib - zz[n_l]) * ss[n_l];
      }
    }
  }
#pragma unroll
  for (int j = 0; j < 4; ++j) {
    int n = n0 + n_j + j;
    out[(size_t)(m0 + m_l) * NN + n] = acc[j] + bias[n];
  }
}

extern "C" void kernel_launch(void* const* d_in, const int* in_sizes, int n_in,
                              void* d_out, int out_size, void* d_ws, size_t ws_size,
                              hipStream_t stream) {
  const float* x      = (const float*)d_in[0];
  const int* qw       = (const int*)d_in[1];
  const int* zeros    = (const int*)d_in[2];
  const float* scales = (const float*)d_in[3];
  const float* bias   = (const float*)d_in[4];
  float* out          = (float*)d_out;

  const size_t x16_bytes = (size_t)MM * KK * 2;   // 33.6 MB

  if (ws_size < x16_bytes) {
    dim3 dg(NN / 32, MM / 32);
    fallback_kernel<<<dg, 256, 0, stream>>>(x, qw, zeros, scales, bias, out);
    return;
  }

  __hip_bfloat16* x16 = (__hip_bfloat16*)d_ws;
  cvt_x_kernel<<<MM * KK / 8 / 256, 256, 0, stream>>>(x, x16);
  dim3 dgm(MM / 256, NN / 256);
  gemm_fused<<<dgm, 512, 0, stream>>>(x16, qw, zeros, scales, bias, out);
}